// Round 10
// baseline (121.076 us; speedup 1.0000x reference)
//
#include <hip/hip_runtime.h>
#include <hip/hip_bf16.h>

// Problem constants
// B=8, C=64, H=256, W=256, NH=4, O=16 (HO=64), MX=32, MY=17
#define NROWS 131072
#define MY 17
#define MX 32

// ws layout (floats):
//   X2:   [4456960, +557056)  [(b*64+c)*32+kx][ky] float2

// ---------------------------------------------------------------------------
// F1 = K1+K2 fused, one (b,c) plane per block, 512 threads. (R8, verified)
// ---------------------------------------------------------------------------
#define K1_ROWS 30
#define NCHUNK 9     // 8*30 + 16 = 256

__global__ __launch_bounds__(512) void f1_fw(const float* __restrict__ x,
                                             float2* __restrict__ X2) {
    __shared__ __align__(16) float s_lds[4][K1_ROWS][68];  // 32640 B
    __shared__ float2 xs[4352];                            // 34816 B  [h*17+ky]
    int t = threadIdx.x;
    int bc = blockIdx.x;  // 0..511
    const float* xp = x + (long)bc * 65536;

    // compute-phase constants: thread t<510: j = t%17, row r = t/17 (0..29)
    int j = t % 17;
    int r = t / 17;
    int rc = r < K1_ROWS ? r : 0;  // clamp for pointer init only
    int odd = j & 1;
    float ca = odd ? 0.f : ((j & 2) ? -1.f : 1.f);
    float cb = odd ? (((j & 3) == 1) ? -1.f : 1.f) : 0.f;
    float cj, sj;
    sincospif((float)j * (1.0f / 128.0f), &sj, &cj);
    sj = -sj;  // step e^{-2pi i j/256}
    float swv, cwv;
    sincospif((float)j * 0.25f, &swv, &cwv);
    swv = -swv;  // w8 = e^{-pi i j/4}
    float k1c = cwv * ca - swv * cb;
    float k2c = swv * ca + cwv * cb;
    const float4* A4 = (const float4*)&s_lds[odd ? 1 : 0][rc][0];
    const float4* B4 = (const float4*)&s_lds[odd ? 3 : 2][rc][0];

    float4 q0, q1, q2, q3;

#define F1_REGLOAD(cc)                                                         \
    {                                                                          \
        int nr_ = ((cc) < 8) ? K1_ROWS : 16;                                   \
        int items_ = nr_ * 16;                                                 \
        int it = t < items_ ? t : items_ - 1;                                  \
        int rr = it >> 4, cq = it & 15;                                        \
        const float4* xr =                                                     \
            (const float4*)(xp + ((cc) * K1_ROWS + rr) * 256) + cq;            \
        q0 = xr[0];                                                            \
        q1 = xr[16];                                                           \
        q2 = xr[32];                                                           \
        q3 = xr[48];                                                           \
    }

    F1_REGLOAD(0)

    for (int c = 0; c < NCHUNK; ++c) {
        int nr = (c < 8) ? K1_ROWS : 16;
        int items = nr * 16;

        // radix-4 combine (along w) + LDS write, from registers
        if (t < items) {
            int rr = t >> 4, cq = t & 15;
            float4 s02p, s02m, s13p, s13m;
            s02p.x = q0.x + q2.x; s02p.y = q0.y + q2.y;
            s02p.z = q0.z + q2.z; s02p.w = q0.w + q2.w;
            s02m.x = q0.x - q2.x; s02m.y = q0.y - q2.y;
            s02m.z = q0.z - q2.z; s02m.w = q0.w - q2.w;
            s13p.x = q1.x + q3.x; s13p.y = q1.y + q3.y;
            s13p.z = q1.z + q3.z; s13p.w = q1.w + q3.w;
            s13m.x = q1.x - q3.x; s13m.y = q1.y - q3.y;
            s13m.z = q1.z - q3.z; s13m.w = q1.w - q3.w;
            *(float4*)&s_lds[0][rr][cq * 4] = s02p;
            *(float4*)&s_lds[1][rr][cq * 4] = s02m;
            *(float4*)&s_lds[2][rr][cq * 4] = s13p;
            *(float4*)&s_lds[3][rr][cq * 4] = s13m;
        }
        __syncthreads();

        // prefetch next chunk into registers (in flight during compute)
        if (c + 1 < NCHUNK) F1_REGLOAD(c + 1)

        // 17-mode DFT of this chunk (radix-2 over l: 32 steps), 1 row/thread
        if (t < 510 && r < nr) {
            float pc = 1.f, ps = 0.f;
            float ar0 = 0, ai0 = 0;

#define K1_STEP(a0e, b0e, a0f, b0f)                                   \
  { float t0re = fmaf(k1c, (b0f), fmaf(cwv, (a0f), fmaf(ca, (b0e), (a0e)))); \
    float t0im = fmaf(k2c, (b0f), fmaf(swv, (a0f), cb * (b0e)));      \
    ar0 = fmaf(t0re, pc, ar0); ar0 = fmaf(-t0im, ps, ar0);            \
    ai0 = fmaf(t0re, ps, ai0); ai0 = fmaf(t0im, pc, ai0);             \
    float nps = fmaf(pc, sj, ps * cj);                                \
    pc = fmaf(pc, cj, -(ps * sj)); ps = nps; }

#pragma unroll 2
            for (int l4 = 0; l4 < 8; ++l4) {
                float4 va0 = A4[l4], vb0 = B4[l4];
                float4 vA0 = A4[8 + l4], vB0 = B4[8 + l4];  // l+32
                K1_STEP(va0.x, vb0.x, vA0.x, vB0.x)
                K1_STEP(va0.y, vb0.y, vA0.y, vB0.y)
                K1_STEP(va0.z, vb0.z, vA0.z, vB0.z)
                K1_STEP(va0.w, vb0.w, vA0.w, vB0.w)
            }
#undef K1_STEP

            int h = c * K1_ROWS + r;
            xs[h * 17 + j] = make_float2(ar0, ai0);
        }
        __syncthreads();
    }

    // K2: in-place radix-4 butterfly along h (stage 1: h vs h+128)
    for (int q = t; q < 2176; q += 512) {
        float2 a = xs[q], b = xs[q + 2176];
        xs[q] = make_float2(a.x + b.x, a.y + b.y);
        xs[q + 2176] = make_float2(a.x - b.x, a.y - b.y);
    }
    __syncthreads();

    for (int q = t; q < 544; q += 512) {
        int kx = q / 17, ky = q % 17;
        int kodd = kx & 1;
        float cA = kodd ? 0.f : ((kx & 2) ? -1.f : 1.f);
        float cB = kodd ? (((kx & 3) == 1) ? -1.f : 1.f) : 0.f;
        float cBn = -cB;
        const float2* Aq = xs + (kodd ? 2176 : 0) + ky;
        float cs, ss;
        sincospif((float)kx * (1.0f / 128.0f), &ss, &cs);
        ss = -ss;  // step e^{-2pi i kx/256}
        float pc = 1.f, psn = 0.f;
        float ar = 0.f, ai = 0.f;
#pragma unroll 4
        for (int m = 0; m < 64; ++m) {
            float2 a = Aq[m * 17];
            float2 b = Aq[1088 + m * 17];
            float yre = fmaf(cBn, b.y, fmaf(cA, b.x, a.x));
            float yim = fmaf(cB, b.x, fmaf(cA, b.y, a.y));
            ar = fmaf(yre, pc, ar); ar = fmaf(-yim, psn, ar);
            ai = fmaf(yre, psn, ai); ai = fmaf(yim, pc, ai);
            float npc = pc * cs - psn * ss;
            psn = pc * ss + psn * cs;
            pc = npc;
        }
        X2[(long)bc * 544 + q] = make_float2(ar, ai);
    }
#undef F1_REGLOAD
}

// ---------------------------------------------------------------------------
// F2B = k3+K4+K5 fused, one (b,ho) plane per block, 512 threads.
//  Phase A (k3): psh[kx][ky] = sum_i X2[b,i,kx,ky] * (wr+i wi)[n,i,o,kx,ky]
//     thread owns q=(kx,ky); all three streams lane-coalesced; X2/W from L2/L3
//  Phase B (K4): zsh[h][ky] = sum_kx psh[kx][ky] e^{+2pi i kx h/256}
//     h = t&255, ky-half by wave group (t>>8)
//  Phase C (K5): out rows from zsh, 8 waves x 2 rows x 16 iters (verified)
// ---------------------------------------------------------------------------
__global__ __launch_bounds__(512) void f2b_inv(const float2* __restrict__ X2,
                                               const float* __restrict__ wr_g,
                                               const float* __restrict__ wi_g,
                                               const float* __restrict__ bias,
                                               float* __restrict__ out) {
    __shared__ float2 psh[544];
    __shared__ float2 zsh[4352];  // [h*17+ky]
    int t = threadIdx.x;
    int plane = blockIdx.x;  // 0..511 = b*64 + ho
    int b = plane >> 6;
    int ho = plane & 63;
    int n = ho >> 4;
    int o = ho & 15;

    // Phase A: per-(kx,ky) 64-deep channel reduction (k3 math, linear i order)
    for (int q = t; q < 544; q += 512) {
        const float2* xp = X2 + (long)b * 64 * 544 + q;
        const float* wrp = wr_g + ((long)(n * 64) * 16 + o) * 544 + q;
        const float* wip = wi_g + ((long)(n * 64) * 16 + o) * 544 + q;
        float ar = 0.f, ai = 0.f;
#pragma unroll 4
        for (int i = 0; i < 64; ++i) {
            float2 xv = xp[i * 544];
            float wvr = wrp[i * 8704];
            float wvi = wip[i * 8704];
            ar += xv.x * wvr - xv.y * wvi;
            ai += xv.x * wvi + xv.y * wvr;
        }
        psh[q] = make_float2(ar, ai);
    }
    __syncthreads();

    // Phase B (K4): h = t&255, half = t>>8 (wave-uniform)
    {
        int h = t & 255;
        int half = t >> 8;
        int kyb = half ? 9 : 0;
        int cnt = half ? 8 : 9;
        float chh, shh;
        sincospif((float)h * (1.0f / 128.0f), &shh, &chh);
        float pc = 1.f, psn = 0.f;
        float ar[9], ai[9];
#pragma unroll
        for (int u = 0; u < 9; ++u) { ar[u] = 0.f; ai[u] = 0.f; }

        const float2* pq = psh + kyb;
        for (int kx = 0; kx < 32; ++kx) {
#pragma unroll
            for (int u = 0; u < 9; ++u) {
                if (u < cnt) {
                    float2 v = pq[kx * 17 + u];
                    ar[u] += v.x * pc - v.y * psn;
                    ai[u] += v.x * psn + v.y * pc;
                }
            }
            float npc = pc * chh - psn * shh;
            psn = pc * shh + psn * chh;
            pc = npc;
        }
#pragma unroll
        for (int u = 0; u < 9; ++u)
            if (u < cnt) zsh[h * 17 + kyb + u] = make_float2(ar[u], ai[u]);
    }
    __syncthreads();

    // Phase C (K5): 8 waves x 2 rows x 16 iters
    int wv = t >> 6;      // 0..7
    int lane = t & 63;
    float bv = bias[plane & 63];
    float c0, s0;
    sincospif((float)lane * (1.0f / 128.0f), &s0, &c0);
    const float inv = 1.0f / 65536.0f;
    const float inv2 = 2.0f / 65536.0f;
    long ob_plane = (long)plane * 65536;

    for (int it16 = 0; it16 < 16; ++it16) {
        int r0 = it16 * 16 + wv * 2;
        float pc = c0, psn = s0;
        float a00 = 0, a01 = 0, a02 = 0, a03 = 0;
        float a10 = 0, a11 = 0, a12 = 0, a13 = 0;

#pragma unroll
        for (int ky = 1; ky <= 16; ++ky) {
            float2 z0 = zsh[r0 * 17 + ky];
            float2 z1 = zsh[(r0 + 1) * 17 + ky];
            float A0 = z0.x * pc - z0.y * psn;
            float B0 = z0.x * psn + z0.y * pc;
            float A1 = z1.x * pc - z1.y * psn;
            float B1 = z1.x * psn + z1.y * pc;
            a00 += A0; a10 += A1;
            a01 += ((ky & 3) == 0) ? A0 : ((ky & 3) == 1) ? -B0 : ((ky & 3) == 2) ? -A0 : B0;
            a11 += ((ky & 3) == 0) ? A1 : ((ky & 3) == 1) ? -B1 : ((ky & 3) == 2) ? -A1 : B1;
            a02 += (ky & 1) ? -A0 : A0;
            a12 += (ky & 1) ? -A1 : A1;
            a03 += ((ky & 3) == 0) ? A0 : ((ky & 3) == 1) ? B0 : ((ky & 3) == 2) ? -A0 : -B0;
            a13 += ((ky & 3) == 0) ? A1 : ((ky & 3) == 1) ? B1 : ((ky & 3) == 2) ? -A1 : -B1;
            float npc = pc * c0 - psn * s0;
            psn = pc * s0 + psn * c0;
            pc = npc;
        }
        float base0 = zsh[r0 * 17].x * inv + bv;
        float base1 = zsh[(r0 + 1) * 17].x * inv + bv;
        long ob0 = ob_plane + (long)r0 * 256;
        long ob1 = ob0 + 256;
        out[ob0 + lane]       = fmaf(a00, inv2, base0);
        out[ob0 + 64 + lane]  = fmaf(a01, inv2, base0);
        out[ob0 + 128 + lane] = fmaf(a02, inv2, base0);
        out[ob0 + 192 + lane] = fmaf(a03, inv2, base0);
        out[ob1 + lane]       = fmaf(a10, inv2, base1);
        out[ob1 + 64 + lane]  = fmaf(a11, inv2, base1);
        out[ob1 + 128 + lane] = fmaf(a12, inv2, base1);
        out[ob1 + 192 + lane] = fmaf(a13, inv2, base1);
    }
}

extern "C" void kernel_launch(void* const* d_in, const int* in_sizes, int n_in,
                              void* d_out, int out_size, void* d_ws, size_t ws_size,
                              hipStream_t stream) {
    const float* x = (const float*)d_in[0];
    const float* wr = (const float*)d_in[1];
    const float* wi = (const float*)d_in[2];
    const float* bias = (const float*)d_in[3];
    float* out = (float*)d_out;
    float* ws = (float*)d_ws;

    float2* X2 = (float2*)(ws + 4456960);

    hipLaunchKernelGGL(f1_fw, dim3(512), dim3(512), 0, stream, x, X2);
    hipLaunchKernelGGL(f2b_inv, dim3(512), dim3(512), 0, stream, X2, wr, wi, bias, out);
}

// Round 11
// 118.524 us; speedup vs baseline: 1.0215x; 1.0215x over previous
//
#include <hip/hip_runtime.h>
#include <hip/hip_bf16.h>

// Problem constants
// B=8, C=64, H=256, W=256, NH=4, O=16 (HO=64), MX=32, MY=17
#define NROWS 131072
#define MY 17
#define MX 32

// ws layout (floats):
//   X2:   [4456960, +557056)  [(b*64+c)*32+kx][ky] float2

// ---------------------------------------------------------------------------
// F1 = K1+K2 fused, one (b,c) plane per block, 512 threads. (R8, verified)
// ---------------------------------------------------------------------------
#define K1_ROWS 30
#define NCHUNK 9     // 8*30 + 16 = 256

__global__ __launch_bounds__(512) void f1_fw(const float* __restrict__ x,
                                             float2* __restrict__ X2) {
    __shared__ __align__(16) float s_lds[4][K1_ROWS][68];  // 32640 B
    __shared__ float2 xs[4352];                            // 34816 B  [h*17+ky]
    int t = threadIdx.x;
    int bc = blockIdx.x;  // 0..511
    const float* xp = x + (long)bc * 65536;

    // compute-phase constants: thread t<510: j = t%17, row r = t/17 (0..29)
    int j = t % 17;
    int r = t / 17;
    int rc = r < K1_ROWS ? r : 0;  // clamp for pointer init only
    int odd = j & 1;
    float ca = odd ? 0.f : ((j & 2) ? -1.f : 1.f);
    float cb = odd ? (((j & 3) == 1) ? -1.f : 1.f) : 0.f;
    float cj, sj;
    sincospif((float)j * (1.0f / 128.0f), &sj, &cj);
    sj = -sj;  // step e^{-2pi i j/256}
    float swv, cwv;
    sincospif((float)j * 0.25f, &swv, &cwv);
    swv = -swv;  // w8 = e^{-pi i j/4}
    float k1c = cwv * ca - swv * cb;
    float k2c = swv * ca + cwv * cb;
    const float4* A4 = (const float4*)&s_lds[odd ? 1 : 0][rc][0];
    const float4* B4 = (const float4*)&s_lds[odd ? 3 : 2][rc][0];

    float4 q0, q1, q2, q3;

#define F1_REGLOAD(cc)                                                         \
    {                                                                          \
        int nr_ = ((cc) < 8) ? K1_ROWS : 16;                                   \
        int items_ = nr_ * 16;                                                 \
        int it = t < items_ ? t : items_ - 1;                                  \
        int rr = it >> 4, cq = it & 15;                                        \
        const float4* xr =                                                     \
            (const float4*)(xp + ((cc) * K1_ROWS + rr) * 256) + cq;            \
        q0 = xr[0];                                                            \
        q1 = xr[16];                                                           \
        q2 = xr[32];                                                           \
        q3 = xr[48];                                                           \
    }

    F1_REGLOAD(0)

    for (int c = 0; c < NCHUNK; ++c) {
        int nr = (c < 8) ? K1_ROWS : 16;
        int items = nr * 16;

        // radix-4 combine (along w) + LDS write, from registers
        if (t < items) {
            int rr = t >> 4, cq = t & 15;
            float4 s02p, s02m, s13p, s13m;
            s02p.x = q0.x + q2.x; s02p.y = q0.y + q2.y;
            s02p.z = q0.z + q2.z; s02p.w = q0.w + q2.w;
            s02m.x = q0.x - q2.x; s02m.y = q0.y - q2.y;
            s02m.z = q0.z - q2.z; s02m.w = q0.w - q2.w;
            s13p.x = q1.x + q3.x; s13p.y = q1.y + q3.y;
            s13p.z = q1.z + q3.z; s13p.w = q1.w + q3.w;
            s13m.x = q1.x - q3.x; s13m.y = q1.y - q3.y;
            s13m.z = q1.z - q3.z; s13m.w = q1.w - q3.w;
            *(float4*)&s_lds[0][rr][cq * 4] = s02p;
            *(float4*)&s_lds[1][rr][cq * 4] = s02m;
            *(float4*)&s_lds[2][rr][cq * 4] = s13p;
            *(float4*)&s_lds[3][rr][cq * 4] = s13m;
        }
        __syncthreads();

        // prefetch next chunk into registers (in flight during compute)
        if (c + 1 < NCHUNK) F1_REGLOAD(c + 1)

        // 17-mode DFT of this chunk (radix-2 over l: 32 steps), 1 row/thread
        if (t < 510 && r < nr) {
            float pc = 1.f, ps = 0.f;
            float ar0 = 0, ai0 = 0;

#define K1_STEP(a0e, b0e, a0f, b0f)                                   \
  { float t0re = fmaf(k1c, (b0f), fmaf(cwv, (a0f), fmaf(ca, (b0e), (a0e)))); \
    float t0im = fmaf(k2c, (b0f), fmaf(swv, (a0f), cb * (b0e)));      \
    ar0 = fmaf(t0re, pc, ar0); ar0 = fmaf(-t0im, ps, ar0);            \
    ai0 = fmaf(t0re, ps, ai0); ai0 = fmaf(t0im, pc, ai0);             \
    float nps = fmaf(pc, sj, ps * cj);                                \
    pc = fmaf(pc, cj, -(ps * sj)); ps = nps; }

#pragma unroll 2
            for (int l4 = 0; l4 < 8; ++l4) {
                float4 va0 = A4[l4], vb0 = B4[l4];
                float4 vA0 = A4[8 + l4], vB0 = B4[8 + l4];  // l+32
                K1_STEP(va0.x, vb0.x, vA0.x, vB0.x)
                K1_STEP(va0.y, vb0.y, vA0.y, vB0.y)
                K1_STEP(va0.z, vb0.z, vA0.z, vB0.z)
                K1_STEP(va0.w, vb0.w, vA0.w, vB0.w)
            }
#undef K1_STEP

            int h = c * K1_ROWS + r;
            xs[h * 17 + j] = make_float2(ar0, ai0);
        }
        __syncthreads();
    }

    // K2: in-place radix-4 butterfly along h (stage 1: h vs h+128)
    for (int q = t; q < 2176; q += 512) {
        float2 a = xs[q], b = xs[q + 2176];
        xs[q] = make_float2(a.x + b.x, a.y + b.y);
        xs[q + 2176] = make_float2(a.x - b.x, a.y - b.y);
    }
    __syncthreads();

    for (int q = t; q < 544; q += 512) {
        int kx = q / 17, ky = q % 17;
        int kodd = kx & 1;
        float cA = kodd ? 0.f : ((kx & 2) ? -1.f : 1.f);
        float cB = kodd ? (((kx & 3) == 1) ? -1.f : 1.f) : 0.f;
        float cBn = -cB;
        const float2* Aq = xs + (kodd ? 2176 : 0) + ky;
        float cs, ss;
        sincospif((float)kx * (1.0f / 128.0f), &ss, &cs);
        ss = -ss;  // step e^{-2pi i kx/256}
        float pc = 1.f, psn = 0.f;
        float ar = 0.f, ai = 0.f;
#pragma unroll 4
        for (int m = 0; m < 64; ++m) {
            float2 a = Aq[m * 17];
            float2 b = Aq[1088 + m * 17];
            float yre = fmaf(cBn, b.y, fmaf(cA, b.x, a.x));
            float yim = fmaf(cB, b.x, fmaf(cA, b.y, a.y));
            ar = fmaf(yre, pc, ar); ar = fmaf(-yim, psn, ar);
            ai = fmaf(yre, psn, ai); ai = fmaf(yim, pc, ai);
            float npc = pc * cs - psn * ss;
            psn = pc * ss + psn * cs;
            pc = npc;
        }
        X2[(long)bc * 544 + q] = make_float2(ar, ai);
    }
#undef F1_REGLOAD
}

// ---------------------------------------------------------------------------
// F2B = k3+K4+K5 fused, one (b,ho) plane per block, 1024 threads (16 waves).
//  Phase A (k3): psh[kx][ky] = sum_i X2[b,i,kx,ky]*(wr+i wi)[n,i,o,kx,ky]
//     q = t < 544 active, linear i order (verified math)
//  Phase B (K4): zsh[h][ky] = sum_kx psh[kx][ky] e^{+2pi i kx h/256}
//     h = t&255; ky group by t>>8: grp0 ky0-4, grp1 5-8, grp2 9-12, grp3 13-16
//  Phase C (K5): 16 waves x 2 rows x 8 iters (verified 2-row inner body)
// ---------------------------------------------------------------------------
__global__ __launch_bounds__(1024) void f2b_inv(const float2* __restrict__ X2,
                                                const float* __restrict__ wr_g,
                                                const float* __restrict__ wi_g,
                                                const float* __restrict__ bias,
                                                float* __restrict__ out) {
    __shared__ float2 psh[544];
    __shared__ float2 zsh[4352];  // [h*17+ky]
    int t = threadIdx.x;
    int plane = blockIdx.x;  // 0..511 = b*64 + ho
    int b = plane >> 6;
    int ho = plane & 63;
    int n = ho >> 4;
    int o = ho & 15;

    // Phase A: per-(kx,ky) 64-deep channel reduction (k3 math, linear i order)
    if (t < 544) {
        int q = t;
        const float2* xp = X2 + (long)b * 64 * 544 + q;
        const float* wrp = wr_g + ((long)(n * 64) * 16 + o) * 544 + q;
        const float* wip = wi_g + ((long)(n * 64) * 16 + o) * 544 + q;
        float ar = 0.f, ai = 0.f;
#pragma unroll 4
        for (int i = 0; i < 64; ++i) {
            float2 xv = xp[i * 544];
            float wvr = wrp[i * 8704];
            float wvi = wip[i * 8704];
            ar += xv.x * wvr - xv.y * wvi;
            ai += xv.x * wvi + xv.y * wvr;
        }
        psh[q] = make_float2(ar, ai);
    }
    __syncthreads();

    // Phase B (K4): h = t&255, ky-group = t>>8 (wave-uniform)
    {
        int h = t & 255;
        int grp = t >> 8;                      // 0..3
        int kyb = (grp == 0) ? 0 : (4 * grp + 1);  // 0,5,9,13
        int cnt = (grp == 0) ? 5 : 4;
        float chh, shh;
        sincospif((float)h * (1.0f / 128.0f), &shh, &chh);
        float pc = 1.f, psn = 0.f;
        float ar[5], ai[5];
#pragma unroll
        for (int u = 0; u < 5; ++u) { ar[u] = 0.f; ai[u] = 0.f; }

        const float2* pq = psh + kyb;
        for (int kx = 0; kx < 32; ++kx) {
#pragma unroll
            for (int u = 0; u < 5; ++u) {
                if (u < cnt) {
                    float2 v = pq[kx * 17 + u];
                    ar[u] += v.x * pc - v.y * psn;
                    ai[u] += v.x * psn + v.y * pc;
                }
            }
            float npc = pc * chh - psn * shh;
            psn = pc * shh + psn * chh;
            pc = npc;
        }
#pragma unroll
        for (int u = 0; u < 5; ++u)
            if (u < cnt) zsh[h * 17 + kyb + u] = make_float2(ar[u], ai[u]);
    }
    __syncthreads();

    // Phase C (K5): 16 waves x 2 rows x 8 iters
    int wv = t >> 6;      // 0..15
    int lane = t & 63;
    float bv = bias[plane & 63];
    float c0, s0;
    sincospif((float)lane * (1.0f / 128.0f), &s0, &c0);
    const float inv = 1.0f / 65536.0f;
    const float inv2 = 2.0f / 65536.0f;
    long ob_plane = (long)plane * 65536;

    for (int it16 = 0; it16 < 8; ++it16) {
        int r0 = it16 * 32 + wv * 2;
        float pc = c0, psn = s0;
        float a00 = 0, a01 = 0, a02 = 0, a03 = 0;
        float a10 = 0, a11 = 0, a12 = 0, a13 = 0;

#pragma unroll
        for (int ky = 1; ky <= 16; ++ky) {
            float2 z0 = zsh[r0 * 17 + ky];
            float2 z1 = zsh[(r0 + 1) * 17 + ky];
            float A0 = z0.x * pc - z0.y * psn;
            float B0 = z0.x * psn + z0.y * pc;
            float A1 = z1.x * pc - z1.y * psn;
            float B1 = z1.x * psn + z1.y * pc;
            a00 += A0; a10 += A1;
            a01 += ((ky & 3) == 0) ? A0 : ((ky & 3) == 1) ? -B0 : ((ky & 3) == 2) ? -A0 : B0;
            a11 += ((ky & 3) == 0) ? A1 : ((ky & 3) == 1) ? -B1 : ((ky & 3) == 2) ? -A1 : B1;
            a02 += (ky & 1) ? -A0 : A0;
            a12 += (ky & 1) ? -A1 : A1;
            a03 += ((ky & 3) == 0) ? A0 : ((ky & 3) == 1) ? B0 : ((ky & 3) == 2) ? -A0 : -B0;
            a13 += ((ky & 3) == 0) ? A1 : ((ky & 3) == 1) ? B1 : ((ky & 3) == 2) ? -A1 : -B1;
            float npc = pc * c0 - psn * s0;
            psn = pc * s0 + psn * c0;
            pc = npc;
        }
        float base0 = zsh[r0 * 17].x * inv + bv;
        float base1 = zsh[(r0 + 1) * 17].x * inv + bv;
        long ob0 = ob_plane + (long)r0 * 256;
        long ob1 = ob0 + 256;
        out[ob0 + lane]       = fmaf(a00, inv2, base0);
        out[ob0 + 64 + lane]  = fmaf(a01, inv2, base0);
        out[ob0 + 128 + lane] = fmaf(a02, inv2, base0);
        out[ob0 + 192 + lane] = fmaf(a03, inv2, base0);
        out[ob1 + lane]       = fmaf(a10, inv2, base1);
        out[ob1 + 64 + lane]  = fmaf(a11, inv2, base1);
        out[ob1 + 128 + lane] = fmaf(a12, inv2, base1);
        out[ob1 + 192 + lane] = fmaf(a13, inv2, base1);
    }
}

extern "C" void kernel_launch(void* const* d_in, const int* in_sizes, int n_in,
                              void* d_out, int out_size, void* d_ws, size_t ws_size,
                              hipStream_t stream) {
    const float* x = (const float*)d_in[0];
    const float* wr = (const float*)d_in[1];
    const float* wi = (const float*)d_in[2];
    const float* bias = (const float*)d_in[3];
    float* out = (float*)d_out;
    float* ws = (float*)d_ws;

    float2* X2 = (float2*)(ws + 4456960);

    hipLaunchKernelGGL(f1_fw, dim3(512), dim3(512), 0, stream, x, X2);
    hipLaunchKernelGGL(f2b_inv, dim3(512), dim3(1024), 0, stream, X2, wr, wi, bias, out);
}